// Round 5
// baseline (470.809 us; speedup 1.0000x reference)
//
#include <hip/hip_runtime.h>
#include <math.h>

#define DD   256
#define HHH  96
#define WWW  96
#define NB   8
#define LL   9216            // HHH*WWW
#define NPIX (NB*LL)         // 73728
#define TCH  32              // scan chunk length
#define NCH  (LL/TCH)        // 288

typedef __bf16 bf16_8 __attribute__((ext_vector_type(8)));
typedef __bf16 bf16_4 __attribute__((ext_vector_type(4)));
typedef float  f32_4  __attribute__((ext_vector_type(4)));

static __device__ __forceinline__ float sigmoidf_(float x) {
    return 1.0f / (1.0f + expf(-x));
}

template<int DIR>
static __device__ __forceinline__ int spidx(int t) {
    if (DIR == 0) return t;
    int w = t / HHH;
    int h = t - w * HHH;
    return h * WWW + w;
}

// ---------------- weight transpose + bf16 cast ----------------
__global__ __launch_bounds__(256) void wcvt_kernel(const float* __restrict__ w_in,
                                                   const float* __restrict__ w_out,
                                                   __bf16* __restrict__ w_inT,
                                                   __bf16* __restrict__ w_outT) {
    int i = blockIdx.x * 256 + threadIdx.x;
    int n = i >> 8, k = i & 255;
    w_inT[i] = (__bf16)w_in[k * 512 + n];
    if (i < 256 * 256) w_outT[i] = (__bf16)w_out[k * 256 + n];
}

// ---------------- LayerNorm: one wave per pixel, shuffle-only ----------------
__global__ __launch_bounds__(256) void ln_kernel(const float* __restrict__ x,
                                                 const float* __restrict__ g,
                                                 const float* __restrict__ b,
                                                 __bf16* __restrict__ h) {
    int wv = threadIdx.x >> 6, lane = threadIdx.x & 63;
    int pix = blockIdx.x * 4 + wv;
    float4 v = *(const float4*)&x[(size_t)pix * DD + lane * 4];
    float s  = v.x + v.y + v.z + v.w;
    float s2 = v.x * v.x + v.y * v.y + v.z * v.z + v.w * v.w;
    #pragma unroll
    for (int o = 32; o > 0; o >>= 1) {
        s  += __shfl_xor(s, o, 64);
        s2 += __shfl_xor(s2, o, 64);
    }
    float mu  = s * (1.0f / 256.0f);
    float var = s2 * (1.0f / 256.0f) - mu * mu;
    float r = rsqrtf(var + 1e-5f);
    float4 gg = *(const float4*)&g[lane * 4];
    float4 bb = *(const float4*)&b[lane * 4];
    bf16_4 o;
    o[0] = (__bf16)((v.x - mu) * r * gg.x + bb.x);
    o[1] = (__bf16)((v.y - mu) * r * gg.y + bb.y);
    o[2] = (__bf16)((v.z - mu) * r * gg.z + bb.z);
    o[3] = (__bf16)((v.w - mu) * r * gg.w + bb.w);
    *(bf16_4*)&h[(size_t)pix * DD + lane * 4] = o;
}

// ---------------- bf16 MFMA GEMM: weight-stationary, barrier-free ----------
// B (128 cols x 256 K) staged in LDS once; each wave streams 64 A-rows from
// global into register fragments; no __syncthreads in the hot loop.
// Block covers 256 rows x 128 cols. Grid: (NPIX/256, N/128).
// MODE 0 (N=512): cols<256 -> x_in (bf16); cols>=256 -> sigmoid -> gate (bf16)
// MODE 1 (N=256): out_f32 = x0 + acc + bias
#define BPITCH 264
template<int MODE>
__global__ __launch_bounds__(256, 2) void gemm_bf16(const __bf16* __restrict__ A,
                                                    const __bf16* __restrict__ BT,
                                                    const float* __restrict__ bias,
                                                    __bf16* __restrict__ out_xin,
                                                    __bf16* __restrict__ out_gate,
                                                    float* __restrict__ out_f32,
                                                    const float* __restrict__ x0) {
    const int K = 256;
    __shared__ __bf16 Bs[128 * BPITCH];   // 67.6 KB
    int tid = threadIdx.x;
    int lane = tid & 63, wv = tid >> 6;
    int rowBase = blockIdx.x * 256;
    int colBase = blockIdx.y * 128;

    // stage B tile: 128 cols x 256 k (64 KB). Each col = 32 uint4 segments.
    #pragma unroll
    for (int it = 0; it < 16; it++) {
        int f = it * 256 + tid;       // 0..4095
        int col = f >> 5;             // 0..127
        int seg = f & 31;             // 0..31  (seg*8 bf16 = K offset)
        *(uint4*)&Bs[col * BPITCH + seg * 8] =
            *(const uint4*)&BT[(size_t)(colBase + col) * K + seg * 8];
    }
    __syncthreads();

    int fr = lane & 15, fq = lane >> 4;
    int row0 = rowBase + wv * 64;

    f32_4 acc[4][8];
    #pragma unroll
    for (int i = 0; i < 4; i++)
        #pragma unroll
        for (int j = 0; j < 8; j++) acc[i][j] = (f32_4){0.f, 0.f, 0.f, 0.f};

    const __bf16* Ap = A + (size_t)(row0 + fr) * K + fq * 8;
    bf16_8 af[4], afn[4];
    #pragma unroll
    for (int mi = 0; mi < 4; mi++)
        af[mi] = *(const bf16_8*)(Ap + (size_t)mi * 16 * K);

    for (int ks = 0; ks < 8; ks++) {
        if (ks < 7) {
            #pragma unroll
            for (int mi = 0; mi < 4; mi++)
                afn[mi] = *(const bf16_8*)(Ap + (size_t)mi * 16 * K + (ks + 1) * 32);
        }
        bf16_8 bf[8];
        #pragma unroll
        for (int ni = 0; ni < 8; ni++)
            bf[ni] = *(const bf16_8*)&Bs[(ni * 16 + fr) * BPITCH + ks * 32 + fq * 8];
        #pragma unroll
        for (int mi = 0; mi < 4; mi++)
            #pragma unroll
            for (int ni = 0; ni < 8; ni++)
                acc[mi][ni] = __builtin_amdgcn_mfma_f32_16x16x32_bf16(
                    af[mi], bf[ni], acc[mi][ni], 0, 0, 0);
        #pragma unroll
        for (int mi = 0; mi < 4; mi++) af[mi] = afn[mi];
    }

    // epilogue: C/D layout col=lane&15, row=(lane>>4)*4+reg
    int rowW = row0 + fq * 4;
    int colW = colBase + fr;
    #pragma unroll
    for (int mi = 0; mi < 4; mi++) {
        #pragma unroll
        for (int ni = 0; ni < 8; ni++) {
            int col = colW + ni * 16;
            float bv = bias[col];
            #pragma unroll
            for (int r = 0; r < 4; r++) {
                int row = rowW + mi * 16 + r;
                float v = acc[mi][ni][r] + bv;
                if (MODE == 0) {
                    if (col < 256) {
                        out_xin[(size_t)row * 256 + col] = (__bf16)v;
                    } else {
                        out_gate[(size_t)row * 256 + (col - 256)] = (__bf16)sigmoidf_(v);
                    }
                } else {
                    out_f32[(size_t)row * 256 + col] = v + x0[(size_t)row * 256 + col];
                }
            }
        }
    }
}

// ---------------- fused depthwise 3x3 conv + SiLU + row-scan chunk totals ----
static __device__ __forceinline__ void loadcol(const __bf16* __restrict__ xin,
                                               int b, int h, int w, int d,
                                               float c[3]) {
    if (w < 0 || w >= WWW) { c[0] = c[1] = c[2] = 0.f; return; }
    size_t base = ((size_t)b * LL + (size_t)h * WWW + w) * DD + d;
    c[0] = (h > 0)       ? (float)xin[base - (size_t)WWW * DD] : 0.f;
    c[1] = (float)xin[base];
    c[2] = (h + 1 < HHH) ? (float)xin[base + (size_t)WWW * DD] : 0.f;
}

__global__ __launch_bounds__(256) void conv_tot_kernel(const __bf16* __restrict__ xin,
                                                       const float* __restrict__ cw,
                                                       const float* __restrict__ cb,
                                                       const float* __restrict__ a_logit,
                                                       const float* __restrict__ ssm_b,
                                                       __bf16* __restrict__ u,
                                                       float* __restrict__ tot_f,
                                                       float* __restrict__ tot_b) {
    int cx = blockIdx.x, h = blockIdx.y, b = blockIdx.z;
    int d = threadIdx.x;
    int w0 = cx * TCH;
    float k[9];
    #pragma unroll
    for (int i = 0; i < 9; i++) k[i] = cw[i * DD + d];
    float bias = cb[d];
    float a = sigmoidf_(a_logit[d]);
    a = fminf(fmaxf(a, 1e-4f), 1.0f - 1e-4f);
    float bb = ssm_b[d];

    float cl[3], cc[3], cr[3];
    loadcol(xin, b, h, w0 - 1, d, cl);
    loadcol(xin, b, h, w0,     d, cc);
    loadcol(xin, b, h, w0 + 1, d, cr);

    float v[TCH];
    float sf = 0.f;
    size_t outBase = ((size_t)b * LL + (size_t)h * WWW + w0) * DD + d;
    #pragma unroll
    for (int j = 0; j < TCH; j++) {
        float nx[3];
        loadcol(xin, b, h, w0 + j + 2, d, nx);
        float acc = bias;
        acc += k[0] * cl[0] + k[1] * cc[0] + k[2] * cr[0];
        acc += k[3] * cl[1] + k[4] * cc[1] + k[5] * cr[1];
        acc += k[6] * cl[2] + k[7] * cc[2] + k[8] * cr[2];
        float uv = acc * sigmoidf_(acc);
        v[j] = uv;
        u[outBase + (size_t)j * DD] = (__bf16)uv;
        sf = a * sf + bb * uv;
        cl[0] = cc[0]; cl[1] = cc[1]; cl[2] = cc[2];
        cc[0] = cr[0]; cc[1] = cr[1]; cc[2] = cr[2];
        cr[0] = nx[0]; cr[1] = nx[1]; cr[2] = nx[2];
    }
    int chunk = h * 3 + cx;
    tot_f[((size_t)b * NCH + chunk) * DD + d] = sf;
    float sb = 0.f;
    #pragma unroll
    for (int j = TCH - 1; j >= 0; j--) sb = a * sb + bb * v[j];
    tot_b[((size_t)b * NCH + chunk) * DD + d] = sb;
}

// ---------------- scan pass A (col direction) ----------------
__global__ __launch_bounds__(256) void scan_totals_col(const __bf16* __restrict__ u,
                                                       const float* __restrict__ a_logit,
                                                       const float* __restrict__ ssm_b,
                                                       float* __restrict__ tot_f,
                                                       float* __restrict__ tot_b) {
    int blk = blockIdx.x;
    int b = blk / NCH, c = blk - b * NCH;
    int d = threadIdx.x;
    float a = sigmoidf_(a_logit[d]);
    a = fminf(fmaxf(a, 1e-4f), 1.0f - 1e-4f);
    float bb = ssm_b[d];
    size_t base = (size_t)b * LL * DD;
    int t0 = c * TCH;
    float v[TCH];
    #pragma unroll
    for (int j = 0; j < TCH; j++)
        v[j] = (float)u[base + (size_t)spidx<1>(t0 + j) * DD + d];
    float s = 0.f;
    #pragma unroll
    for (int j = 0; j < TCH; j++) s = a * s + bb * v[j];
    tot_f[(size_t)blk * DD + d] = s;
    s = 0.f;
    #pragma unroll
    for (int j = TCH - 1; j >= 0; j--) s = a * s + bb * v[j];
    tot_b[(size_t)blk * DD + d] = s;
}

// ---------------- scan pass B: all 4 carry scans in one dispatch -----------
__global__ __launch_bounds__(256) void scan_carries(const float* __restrict__ tot_all,
                                                    const float* __restrict__ a_logit,
                                                    float* __restrict__ car_all) {
    int b = blockIdx.x;
    int var = blockIdx.y;
    int d = threadIdx.x;
    float a = sigmoidf_(a_logit[d]);
    a = fminf(fmaxf(a, 1e-4f), 1.0f - 1e-4f);
    float a2 = a * a, a4 = a2 * a2, a8 = a4 * a4, a16 = a8 * a8;
    float q = a16 * a16;    // a^TCH
    const float* tot = tot_all + (size_t)var * NB * NCH * DD + (size_t)b * NCH * DD + d;
    float* car = car_all + (size_t)var * NB * NCH * DD + (size_t)b * NCH * DD + d;
    float P = 0.f;
    if ((var & 1) == 0) {
        for (int c0 = 0; c0 < NCH; c0 += 8) {
            float t[8];
            #pragma unroll
            for (int j = 0; j < 8; j++) t[j] = tot[(size_t)(c0 + j) * DD];
            #pragma unroll
            for (int j = 0; j < 8; j++) {
                car[(size_t)(c0 + j) * DD] = P;
                P = q * P + t[j];
            }
        }
    } else {
        for (int c0 = NCH - 8; c0 >= 0; c0 -= 8) {
            float t[8];
            #pragma unroll
            for (int j = 0; j < 8; j++) t[j] = tot[(size_t)(c0 + j) * DD];
            #pragma unroll
            for (int j = 7; j >= 0; j--) {
                car[(size_t)(c0 + j) * DD] = P;
                P = q * P + t[j];
            }
        }
    }
}

// ---------------- scan pass C: apply carries, emit 0.25*(yf+yb) ----------------
// DIR 0: y[idx] = bf16(val)
// DIR 1: g[idx] = bf16((y[idx] + val) * gate[idx])
template<int DIR>
__global__ __launch_bounds__(256) void scan_apply(const __bf16* __restrict__ u,
                                                  const float* __restrict__ a_logit,
                                                  const float* __restrict__ ssm_b,
                                                  const float* __restrict__ ssm_c,
                                                  const float* __restrict__ ssm_d,
                                                  const float* __restrict__ car_f,
                                                  const float* __restrict__ car_b,
                                                  __bf16* __restrict__ y,
                                                  const __bf16* __restrict__ gate,
                                                  __bf16* __restrict__ g) {
    int blk = blockIdx.x;
    int b = blk / NCH, c = blk - b * NCH;
    int d = threadIdx.x;
    float a = sigmoidf_(a_logit[d]);
    a = fminf(fmaxf(a, 1e-4f), 1.0f - 1e-4f);
    float bb = ssm_b[d], cc = ssm_c[d], dd = ssm_d[d];
    size_t base = (size_t)b * LL * DD;
    int t0 = c * TCH;
    float v[TCH];
    #pragma unroll
    for (int j = 0; j < TCH; j++)
        v[j] = (float)u[base + (size_t)spidx<DIR>(t0 + j) * DD + d];
    float yf[TCH];
    float s = car_f[(size_t)blk * DD + d];
    #pragma unroll
    for (int j = 0; j < TCH; j++) {
        s = a * s + bb * v[j];
        yf[j] = cc * s + dd * v[j];
    }
    s = car_b[(size_t)blk * DD + d];
    #pragma unroll
    for (int j = TCH - 1; j >= 0; j--) {
        s = a * s + bb * v[j];
        float val = 0.25f * (yf[j] + cc * s + dd * v[j]);
        size_t idx = base + (size_t)spidx<DIR>(t0 + j) * DD + d;
        if (DIR == 0) {
            y[idx] = (__bf16)val;
        } else {
            float t = (float)y[idx] + val;
            g[idx] = (__bf16)(t * (float)gate[idx]);
        }
    }
}

extern "C" void kernel_launch(void* const* d_in, const int* in_sizes, int n_in,
                              void* d_out, int out_size, void* d_ws, size_t ws_size,
                              hipStream_t stream) {
    const float* x       = (const float*)d_in[0];
    const float* ln_g    = (const float*)d_in[1];
    const float* ln_b    = (const float*)d_in[2];
    const float* w_in    = (const float*)d_in[3];
    const float* b_in    = (const float*)d_in[4];
    const float* conv_w  = (const float*)d_in[5];
    const float* conv_b  = (const float*)d_in[6];
    const float* a_logit = (const float*)d_in[7];
    const float* ssm_b   = (const float*)d_in[8];
    const float* ssm_c   = (const float*)d_in[9];
    const float* ssm_d   = (const float*)d_in[10];
    const float* w_out   = (const float*)d_in[11];
    const float* b_out   = (const float*)d_in[12];
    float* out = (float*)d_out;

    char* ws = (char*)d_ws;
    const size_t SZH = (size_t)NPIX * DD * sizeof(__bf16);    // 37.7 MB
    const size_t TS  = (size_t)NB * NCH * DD * sizeof(float); // 2.36 MB

    __bf16* hB     = (__bf16*)(ws);                  // h, later reused as g
    __bf16* xinB   = (__bf16*)(ws + SZH);            // x_in bf16; reused as y bf16
    __bf16* uB     = (__bf16*)(ws + 2 * SZH);        // conv output bf16
    __bf16* gateB  = (__bf16*)(ws + 3 * SZH);        // gate bf16
    float*  tot    = (float*)(ws + 4 * SZH);         // [4][NB][NCH][DD]
    float*  car    = (float*)(ws + 4 * SZH + 4 * TS);
    __bf16* w_inT  = (__bf16*)(ws + 4 * SZH + 8 * TS);
    __bf16* w_outT = w_inT + 512 * 256;
    __bf16* yB     = xinB;                           // x_in dead after conv_tot

    wcvt_kernel<<<512, 256, 0, stream>>>(w_in, w_out, w_inT, w_outT);
    ln_kernel<<<NPIX / 4, 256, 0, stream>>>(x, ln_g, ln_b, hB);
    gemm_bf16<0><<<dim3(NPIX / 256, 4), 256, 0, stream>>>(hB, w_inT, b_in,
                                                          xinB, gateB, nullptr, nullptr);
    // fused conv + row totals
    conv_tot_kernel<<<dim3(WWW / TCH, HHH, NB), 256, 0, stream>>>(
        xinB, conv_w, conv_b, a_logit, ssm_b, uB,
        tot + 0 * (size_t)NB * NCH * DD, tot + 1 * (size_t)NB * NCH * DD);
    // col totals
    scan_totals_col<<<NB * NCH, 256, 0, stream>>>(
        uB, a_logit, ssm_b,
        tot + 2 * (size_t)NB * NCH * DD, tot + 3 * (size_t)NB * NCH * DD);
    // all 4 carry scans
    scan_carries<<<dim3(NB, 4), 256, 0, stream>>>(tot, a_logit, car);
    // row apply -> y (bf16, reuses x_in slot)
    scan_apply<0><<<NB * NCH, 256, 0, stream>>>(
        uB, a_logit, ssm_b, ssm_c, ssm_d,
        car + 0 * (size_t)NB * NCH * DD, car + 1 * (size_t)NB * NCH * DD,
        yB, nullptr, nullptr);
    // col apply + gate -> g (bf16, reuses h slot)
    scan_apply<1><<<NB * NCH, 256, 0, stream>>>(
        uB, a_logit, ssm_b, ssm_c, ssm_d,
        car + 2 * (size_t)NB * NCH * DD, car + 3 * (size_t)NB * NCH * DD,
        yB, gateB, hB);
    // out = x0 + g @ w_out + b_out
    gemm_bf16<1><<<dim3(NPIX / 256, 2), 256, 0, stream>>>(hB, w_outT, b_out,
                                                          nullptr, nullptr, out, x);
}